// Round 11
// baseline (377.287 us; speedup 1.0000x reference)
//
#include <hip/hip_runtime.h>

#define BB 512
#define TT 2048

// ---------- fast math helpers ----------
__device__ __forceinline__ float fexp2(float x){ return __builtin_amdgcn_exp2f(x); }
__device__ __forceinline__ float frcp(float x){ return __builtin_amdgcn_rcpf(x); }

#define QB(v, ctrl) __int_as_float(__builtin_amdgcn_mov_dpp(__float_as_int(v), (ctrl), 0xF, 0xF, true))
#define RL(v, l)    __builtin_amdgcn_readlane((v), (l))

// ---------- round 11: single self-producing wave ----------
// One wave per batch element (512 blocks x 64). The wave runs the 240cy/step
// recurrence AND produces its own input projections ONE ROW (8 steps) AHEAD:
//   - x row g+1 lives in 2 per-lane VGPRs (coalesced loads, prefetched 2 rows ahead)
//   - during row g's 8 STEPs, each step u broadcasts 13 x values via readlane
//     (placed between the DPP trio and the c-chain, where ~30-50cy of
//     transcendental stalls absorb their issue) and accumulates
//     sxB[u] = kq*(bias + Wih_row . x) with 13 sinkable FMAs.
//   - row rotate: sxA <- sxB, xr <- xn.
// Round-1's failure (sx chain spliced into the critical path: computed
// immediately before use) is structurally eliminated by the 8-step production
// distance; the sx serial chain (52cy) amortizes over ~1900cy.
// No pass 1, no LDS, no barriers, no second wave. fp32 seeds (was f16).
// lane 4j+q = gate q of unit j; lane 52 = fused FC row (sxw=0, bias=-log2e*fc_b).
__global__ __launch_bounds__(64, 1) void k_sp(
    const float* __restrict__ x,
    const float* __restrict__ Wih,
    const float* __restrict__ Whh,
    const float* __restrict__ bih,
    const float* __restrict__ bhh,
    const float* __restrict__ fcw,
    const float* __restrict__ fcb,
    float* __restrict__ out)
{
  const int lane = threadIdx.x;
  const int b    = blockIdx.x;
  const int q    = lane & 3;
  const int j    = lane >> 2;             // 0..15 (13..15 padding)
  const int jc   = (j < 13) ? j : 12;
  const bool fcl = (lane == 52);
  const int e    = fcl ? 52 : q*13 + jc;
  const int er   = fcl ? 0  : q*13 + jc;  // row index for Wih (lane52 unused row 0)

  const float kq = (q==2) ? -2.8853900817779268f : -1.4426950408889634f;
  const float gm = (q==2) ? -5.7707801635558536f : 1.f;
  const float ga = (q==2) ?  2.8853900817779268f : 0.f;
  const float fcbias = -1.4426950408889634f * fcb[0];

  // recurrent weights (consumer): Whh row scaled by kq; lane52 = fcw * (-log2e)
  const float* wsrc = fcl ? fcw : (Whh + (size_t)e*13);
  float w[13];
  #pragma unroll
  for (int k=0;k<13;k++) w[k] = wsrc[k]*kq;

  // input-projection weights (producer role of the SAME lane): Wih row scaled
  // by kq; lane52 produces the constant FC row -> sxw = 0.
  const float kx = fcl ? 0.f : kq;
  float sxw[13];
  #pragma unroll
  for (int k=0;k<13;k++) sxw[k] = Wih[er*13+k]*kx;
  const float biass = fcl ? fcbias : (bih[e]+bhh[e])*kq;

  // x row staging: row = 8 steps x 13 feats = 104 floats across 2 per-lane regs.
  // flat f = u*13+k: reg f>>6, lane f&63 (xr1 uses lanes 0..39 only).
  const float* xb = x + (size_t)b*(TT*13);
  const int lane2 = (lane < 40) ? lane : 39;      // keep xr1 load in-bounds

  float h = 0.f, c_ = 0.f;                // c_ carries -2*log2e*c
  float hb0=0,hb1=0,hb2=0,hb3=0,hb4=0,hb5=0,hb6=0,hb7=0,hb8=0,hb9=0,hb10=0,hb11=0,hb12=0;
  float p0=0,p1=0,p2=0,p3=0,p4=0,p5=0,p6=0,p7=0;
  float* op = out + (size_t)b*TT;
  bool first = true;

  float sxA[8], sxB[8];                   // compile-time indices only
  float xr0, xr1, xn0, xn1;

#define RLX(f_) __int_as_float(RL(__float_as_int(((f_) < 64) ? xr0 : xr1), (f_) & 63))

#define CAPTURE(gv_, u_) do {                                                 \
    if ((u_)==1) p0=(gv_); else if ((u_)==2) p1=(gv_);                        \
    else if ((u_)==3) p2=(gv_); else if ((u_)==4) p3=(gv_);                   \
    else if ((u_)==5) p4=(gv_); else if ((u_)==6) p5=(gv_);                   \
    else if ((u_)==7) p6=(gv_);                                               \
    else { p7=(gv_);                                                          \
      if (!first){                                                            \
        if (lane == 52){                                                      \
          float4* o4 = (float4*)op;                                           \
          o4[0] = make_float4(p0,p1,p2,p3);                                   \
          o4[1] = make_float4(p4,p5,p6,p7);                                   \
        }                                                                     \
        op += 8;                                                              \
      }                                                                       \
      first = false;                                                          \
    }                                                                         \
  } while(0)

// one recurrence step (k_rec7 math, fp32 seed) + next-row sx production for
// the same step index. tx readlanes sit in the c-chain stall window; the sx
// FMA chain is sinkable and has 8 steps of slack before consumption.
#define STEPU(u_) do {                                                        \
    float dA = fmaf(w[0], hb0, sxA[u_]);                                      \
    dA = fmaf(w[1], hb1, dA);                                                 \
    dA = fmaf(w[2], hb2, dA);                                                 \
    dA = fmaf(w[3], hb3, dA);                                                 \
    dA = fmaf(w[4], hb4, dA);                                                 \
    float dB = w[5]*hb5;                                                      \
    dB = fmaf(w[6], hb6, dB);                                                 \
    dB = fmaf(w[7], hb7, dB);                                                 \
    dB = fmaf(w[8], hb8, dB);                                                 \
    float dC = w[9]*hb9;                                                      \
    dC = fmaf(w[10], hb10, dC);                                               \
    dC = fmaf(w[11], hb11, dC);                                               \
    dC = fmaf(w[12], hb12, dC);                                               \
    float s  = (dB + dC) + dA;                                                \
    float r  = frcp(1.f + fexp2(s));                                          \
    float g  = fmaf(gm, r, ga);                                               \
    CAPTURE(g, u_);                                                           \
    float ggb = QB(g, 0xAA);                                                  \
    float gfb = QB(g, 0x55);                                                  \
    float gob = QB(g, 0xFF);                                                  \
    float tx0  = RLX((u_)*13+0);                                              \
    float tx1  = RLX((u_)*13+1);                                              \
    float tx2  = RLX((u_)*13+2);                                              \
    float tx3  = RLX((u_)*13+3);                                              \
    float tx4  = RLX((u_)*13+4);                                              \
    float tx5  = RLX((u_)*13+5);                                              \
    float tx6  = RLX((u_)*13+6);                                              \
    float tx7  = RLX((u_)*13+7);                                              \
    float tx8  = RLX((u_)*13+8);                                              \
    float tx9  = RLX((u_)*13+9);                                              \
    float tx10 = RLX((u_)*13+10);                                             \
    float tx11 = RLX((u_)*13+11);                                             \
    float tx12 = RLX((u_)*13+12);                                             \
    float go2 = gob + gob;                                                    \
    c_ = fmaf(gfb, c_, g*ggb);                                                \
    float r2 = frcp(1.f + fexp2(c_));                                         \
    h = fmaf(go2, r2, -gob);                                                  \
    int hv_ = __float_as_int(h);                                              \
    hb0  = __int_as_float(RL(hv_, 0));                                        \
    hb1  = __int_as_float(RL(hv_, 4));                                        \
    hb2  = __int_as_float(RL(hv_, 8));                                        \
    hb3  = __int_as_float(RL(hv_, 12));                                       \
    hb4  = __int_as_float(RL(hv_, 16));                                       \
    hb5  = __int_as_float(RL(hv_, 20));                                       \
    hb6  = __int_as_float(RL(hv_, 24));                                       \
    hb7  = __int_as_float(RL(hv_, 28));                                       \
    hb8  = __int_as_float(RL(hv_, 32));                                       \
    hb9  = __int_as_float(RL(hv_, 36));                                       \
    hb10 = __int_as_float(RL(hv_, 40));                                       \
    hb11 = __int_as_float(RL(hv_, 44));                                       \
    hb12 = __int_as_float(RL(hv_, 48));                                       \
    float a_ = biass;                                                         \
    a_ = fmaf(sxw[0],  tx0,  a_);                                             \
    a_ = fmaf(sxw[1],  tx1,  a_);                                             \
    a_ = fmaf(sxw[2],  tx2,  a_);                                             \
    a_ = fmaf(sxw[3],  tx3,  a_);                                             \
    a_ = fmaf(sxw[4],  tx4,  a_);                                             \
    a_ = fmaf(sxw[5],  tx5,  a_);                                             \
    a_ = fmaf(sxw[6],  tx6,  a_);                                             \
    a_ = fmaf(sxw[7],  tx7,  a_);                                             \
    a_ = fmaf(sxw[8],  tx8,  a_);                                             \
    a_ = fmaf(sxw[9],  tx9,  a_);                                             \
    a_ = fmaf(sxw[10], tx10, a_);                                             \
    a_ = fmaf(sxw[11], tx11, a_);                                             \
    a_ = fmaf(sxw[12], tx12, a_);                                             \
    sxB[u_] = a_;                                                             \
  } while(0)

// prologue-only: compute sxA[u_] for row 0 directly (off any critical path)
#define SXINIT(u_) do {                                                       \
    float a_ = biass;                                                         \
    _Pragma("unroll")                                                         \
    for (int k_=0;k_<13;++k_)                                                 \
      a_ = fmaf(sxw[k_], RLX((u_)*13+k_), a_);                                \
    sxA[u_] = a_;                                                             \
  } while(0)

  // -------- prologue: row 0 seeds, then stage row 1, prefetch row 2 --------
  xr0 = xb[lane];  xr1 = xb[64+lane2];              // row 0
  SXINIT(0); SXINIT(1); SXINIT(2); SXINIT(3);
  SXINIT(4); SXINIT(5); SXINIT(6); SXINIT(7);
  xr0 = xb[104+lane];  xr1 = xb[104+64+lane2];      // row 1 (produced during row 0)

  // -------- main loop: 256 rows of 8 steps --------
  for (int gi=0; gi<256; ++gi){
    const int gp = (gi+2 < 256) ? (gi+2) : 255;     // clamped prefetch row
    const float* rp = xb + (size_t)gp*104;
    xn0 = rp[lane];  xn1 = rp[64+lane2];
    STEPU(0); STEPU(1); STEPU(2); STEPU(3);
    STEPU(4); STEPU(5); STEPU(6); STEPU(7);
    #pragma unroll
    for (int u=0;u<8;++u) sxA[u] = sxB[u];
    xr0 = xn0;  xr1 = xn1;                          // vmcnt wait lands here (free)
  }

  // -------- epilogue: out[2047] = sigmoid(fc_b + fc_w·h_2047) --------
  {
    float s = fcbias;
    s = fmaf(w[0],  hb0,  s);
    s = fmaf(w[1],  hb1,  s);
    s = fmaf(w[2],  hb2,  s);
    s = fmaf(w[3],  hb3,  s);
    s = fmaf(w[4],  hb4,  s);
    s = fmaf(w[5],  hb5,  s);
    s = fmaf(w[6],  hb6,  s);
    s = fmaf(w[7],  hb7,  s);
    s = fmaf(w[8],  hb8,  s);
    s = fmaf(w[9],  hb9,  s);
    s = fmaf(w[10], hb10, s);
    s = fmaf(w[11], hb11, s);
    s = fmaf(w[12], hb12, s);
    float r = frcp(1.f + fexp2(s));
    if (lane == 52){
      float4* o4 = (float4*)op;                     // op == out + b*TT + 2040 here
      o4[0] = make_float4(p0,p1,p2,p3);
      o4[1] = make_float4(p4,p5,p6,r);
    }
  }

#undef SXINIT
#undef STEPU
#undef CAPTURE
#undef RLX
}

extern "C" void kernel_launch(void* const* d_in, const int* in_sizes, int n_in,
                              void* d_out, int out_size, void* d_ws, size_t ws_size,
                              hipStream_t stream)
{
  const float* x   = (const float*)d_in[0];
  const float* Wih = (const float*)d_in[1];
  const float* Whh = (const float*)d_in[2];
  const float* bih = (const float*)d_in[3];
  const float* bhh = (const float*)d_in[4];
  const float* fcw = (const float*)d_in[5];
  const float* fcb = (const float*)d_in[6];
  float* out = (float*)d_out;

  (void)d_ws; (void)ws_size;   // fully fused, single wave per chain: no workspace
  k_sp<<<dim3(BB), dim3(64), 0, stream>>>(x, Wih, Whh, bih, bhh, fcw, fcb, out);
}

// Round 12
// 307.433 us; speedup vs baseline: 1.2272x; 1.2272x over previous
//
#include <hip/hip_runtime.h>
#include <hip/hip_fp16.h>

#define BB 512
#define TT 2048

typedef _Float16 half2v __attribute__((ext_vector_type(2)));

// ---------- fast math helpers ----------
__device__ __forceinline__ float fexp2(float x){ return __builtin_amdgcn_exp2f(x); }
__device__ __forceinline__ float frcp(float x){ return __builtin_amdgcn_rcpf(x); }

#define QB(v, ctrl) __int_as_float(__builtin_amdgcn_mov_dpp(__float_as_int(v), (ctrl), 0xF, 0xF, true))
#define RL(v, l)    __builtin_amdgcn_readlane((v), (l))

// ---------- fused producer/consumer (round-6 optimum, reinstated) ----------
// Block = 128 threads (2 waves) per batch element b.
//   Consumer seed path is BYTE-IDENTICAL to the proven 205us k_rec7 (f16 rows,
//   uint4/ds_read_b128 loads, 848B/tg layout) -- only the address space changed
//   (global xg -> LDS chunk). Producer emits the exact k_xg3 row format.
//   LDS: 2 chunk buffers x 8 tg x 424 ushorts (53 rows x 8 f16) = 13,568 B.
//   producer (wave 1): per chunk, 52 dots of 13 (weights via scalar cache, x via
//     13 coalesced per-lane dwords prefetched one chunk ahead) + f16 cvt +
//     ds_write_b16. Always early vs the consumer's ~15.4K cy chunk.
//   consumer (wave 0): k_rec7 verbatim. lane 4j+q = gate q of unit j; lane 52
//     computes the fused FC output in-stream. Per chunk: 8x ds_read_b128, 64 STEPs.
//   sync: 1 __syncthreads per 64 steps (32 total), double-buffered.
// Search record (rounds 7-11): setprio -50us; I$ shrink -53us; early-XLOAD
// neutral; CH=128 -100us; dual-chain -150us; in-wave self-production -100us.
// Every perturbation regressed or was neutral -> this is the measured optimum.
__global__ __launch_bounds__(128, 1) void k_pc(
    const float* __restrict__ x,
    const float* __restrict__ Wih,
    const float* __restrict__ Whh,
    const float* __restrict__ bih,
    const float* __restrict__ bhh,
    const float* __restrict__ fcw,
    const float* __restrict__ fcb,
    float* __restrict__ out)
{
  __shared__ unsigned short xgb[2][8][424];   // [buf][tg][53 rows x 8 u]

  const int tid  = threadIdx.x;
  const int wid  = tid >> 6;
  const int lane = tid & 63;
  const int b    = blockIdx.x;

  // ---- producer state (persists across chunk loop)
  float xr[13];
  const int  tgl = lane >> 3, u = lane & 7;
  const float* xbase = x + ((size_t)b*TT + tgl*8 + u)*13;   // t = c*64 + tgl*8 + u
  unsigned short fc16 = 0;

  // ---- consumer state (persists across chunk loop; k_rec7 verbatim)
  float w[13];
  float gm = 1.f, ga = 0.f, fcbias = 0.f;
  int   e = 0;
  float h = 0.f, c_ = 0.f;            // c_ carries -2*log2e*c
  float hb0=0,hb1=0,hb2=0,hb3=0,hb4=0,hb5=0,hb6=0,hb7=0,hb8=0,hb9=0,hb10=0,hb11=0,hb12=0;
  float p0=0,p1=0,p2=0,p3=0,p4=0,p5=0,p6=0,p7=0;
  float* op = out + (size_t)b*TT;
  bool first = true;

// producer: load chunk c_'s 13 x values (coalesced per-lane dwords; issued one
// chunk ahead -- the full consumer chunk (~15K cy) covers HBM latency)
#define XLOAD(c_) do {                                                        \
    const float* p_ = xbase + (size_t)(c_)*64*13;                             \
    _Pragma("unroll")                                                         \
    for (int k=0;k<13;++k) xr[k] = p_[k];                                     \
  } while(0)

// producer: compute + write one chunk in the exact k_xg3 row format
#define FILL(bi_) do {                                                        \
    unsigned short* dst_ = &xgb[bi_][tgl][0];                                 \
    _Pragma("unroll 4")                                                       \
    for (int g=0; g<52; ++g){                                                 \
      float acc = bih[g] + bhh[g];                                            \
      _Pragma("unroll")                                                       \
      for (int k=0;k<13;++k) acc = fmaf(Wih[g*13+k], xr[k], acc);             \
      const float sc = (g>=26 && g<39) ? -2.8853900817779268f                 \
                                       : -1.4426950408889634f;                \
      dst_[g*8 + u] = __half_as_ushort(__float2half(acc*sc));                 \
    }                                                                         \
    dst_[52*8 + u] = fc16;                                                    \
  } while(0)

#define CAPTURE(gv_, u_) do {                                                 \
    if ((u_)==1) p0=(gv_); else if ((u_)==2) p1=(gv_);                        \
    else if ((u_)==3) p2=(gv_); else if ((u_)==4) p3=(gv_);                   \
    else if ((u_)==5) p4=(gv_); else if ((u_)==6) p5=(gv_);                   \
    else if ((u_)==7) p6=(gv_);                                               \
    else { p7=(gv_);                                                          \
      if (!first){                                                            \
        if (lane == 52){                                                      \
          float4* o4 = (float4*)op;                                           \
          o4[0] = make_float4(p0,p1,p2,p3);                                   \
          o4[1] = make_float4(p4,p5,p6,p7);                                   \
        }                                                                     \
        op += 8;                                                              \
      }                                                                       \
      first = false;                                                          \
    }                                                                         \
  } while(0)

#define STEP(xv_, u_) do {                                                    \
    float dA = fmaf(w[0], hb0, (xv_));                                        \
    dA = fmaf(w[1], hb1, dA);                                                 \
    dA = fmaf(w[2], hb2, dA);                                                 \
    dA = fmaf(w[3], hb3, dA);                                                 \
    dA = fmaf(w[4], hb4, dA);                                                 \
    float dB = w[5]*hb5;                                                      \
    dB = fmaf(w[6], hb6, dB);                                                 \
    dB = fmaf(w[7], hb7, dB);                                                 \
    dB = fmaf(w[8], hb8, dB);                                                 \
    float dC = w[9]*hb9;                                                      \
    dC = fmaf(w[10], hb10, dC);                                               \
    dC = fmaf(w[11], hb11, dC);                                               \
    dC = fmaf(w[12], hb12, dC);                                               \
    float s  = (dB + dC) + dA;                                                \
    float r  = frcp(1.f + fexp2(s));                                          \
    float g  = fmaf(gm, r, ga);                                               \
    CAPTURE(g, u_);                                                           \
    float ggb = QB(g, 0xAA);                                                  \
    float gfb = QB(g, 0x55);                                                  \
    float gob = QB(g, 0xFF);                                                  \
    float go2 = gob + gob;                                                    \
    c_ = fmaf(gfb, c_, g*ggb);                                                \
    float r2 = frcp(1.f + fexp2(c_));                                         \
    h = fmaf(go2, r2, -gob);                                                  \
    int hv_ = __float_as_int(h);                                              \
    hb0  = __int_as_float(RL(hv_, 0));                                        \
    hb1  = __int_as_float(RL(hv_, 4));                                        \
    hb2  = __int_as_float(RL(hv_, 8));                                        \
    hb3  = __int_as_float(RL(hv_, 12));                                       \
    hb4  = __int_as_float(RL(hv_, 16));                                       \
    hb5  = __int_as_float(RL(hv_, 20));                                       \
    hb6  = __int_as_float(RL(hv_, 24));                                       \
    hb7  = __int_as_float(RL(hv_, 28));                                       \
    hb8  = __int_as_float(RL(hv_, 32));                                       \
    hb9  = __int_as_float(RL(hv_, 36));                                       \
    hb10 = __int_as_float(RL(hv_, 40));                                       \
    hb11 = __int_as_float(RL(hv_, 44));                                       \
    hb12 = __int_as_float(RL(hv_, 48));                                       \
  } while(0)

#define XLO(w_) (float)(__builtin_bit_cast(half2v, (w_)).x)
#define XHI(w_) (float)(__builtin_bit_cast(half2v, (w_)).y)

#define STEP8(Q) do {                                                         \
    STEP(XLO(Q.x), 0); STEP(XHI(Q.x), 1);                                     \
    STEP(XLO(Q.y), 2); STEP(XHI(Q.y), 3);                                     \
    STEP(XLO(Q.z), 4); STEP(XHI(Q.z), 5);                                     \
    STEP(XLO(Q.w), 6); STEP(XHI(Q.w), 7);                                     \
  } while(0)

// consumer: one chunk = 8 tg rows, k_rec7's uint4 row loads from LDS
#define CONSUME(bi_) do {                                                     \
    const char* base_ = (const char*)&xgb[bi_][0][0] + (size_t)e*16;          \
    uint4 r0 = *(const uint4*)(base_ + 0*848);                                \
    uint4 r1 = *(const uint4*)(base_ + 1*848);                                \
    uint4 r2 = *(const uint4*)(base_ + 2*848);                                \
    uint4 r3 = *(const uint4*)(base_ + 3*848);                                \
    uint4 r4 = *(const uint4*)(base_ + 4*848);                                \
    uint4 r5 = *(const uint4*)(base_ + 5*848);                                \
    uint4 r6 = *(const uint4*)(base_ + 6*848);                                \
    uint4 r7 = *(const uint4*)(base_ + 7*848);                                \
    STEP8(r0); STEP8(r1); STEP8(r2); STEP8(r3);                               \
    STEP8(r4); STEP8(r5); STEP8(r6); STEP8(r7);                               \
  } while(0)

  if (wid == 1){
    // -------- producer setup + chunk 0 --------
    fc16 = __half_as_ushort(__float2half(-1.4426950408889634f * fcb[0]));
    XLOAD(0);
    FILL(0);
    XLOAD(1);                 // prefetch chunk 1 (consumed next FILL)
  } else {
    // -------- consumer setup (k_rec7 verbatim) --------
    const int q  = lane & 3;
    const int j  = lane >> 2;             // 0..15 (13..15 padding)
    const int jc = (j < 13) ? j : 12;
    e = (lane == 52) ? 52 : q*13 + jc;
    const float kq = (q==2) ? -2.8853900817779268f : -1.4426950408889634f;
    gm = (q==2) ? -5.7707801635558536f : 1.f;
    ga = (q==2) ?  2.8853900817779268f : 0.f;
    fcbias = -1.4426950408889634f * fcb[0];
    const float* wsrc = (lane == 52) ? fcw : (Whh + (size_t)e*13);
    #pragma unroll
    for (int k=0;k<13;k++) w[k] = wsrc[k]*kq;
  }
  __syncthreads();                                  // chunk 0 ready

  for (int c=0; c<31; ++c){
    if (wid == 1){
      FILL((c+1)&1);                                // chunk c+1 (uses prefetched xr)
      if (c < 30) XLOAD(c+2);                       // prefetch chunk c+2
    } else {
      CONSUME(c&1);                                 // chunk c
    }
    __syncthreads();                                // chunk c+1 ready
  }

  if (wid == 0){
    CONSUME(31&1);                                  // chunk 31

    // epilogue: out[2047] = sigmoid(fc_b + fc_w·h_2047); lane 52 stores p0..p6 + r
    float s = fcbias;
    s = fmaf(w[0],  hb0,  s);
    s = fmaf(w[1],  hb1,  s);
    s = fmaf(w[2],  hb2,  s);
    s = fmaf(w[3],  hb3,  s);
    s = fmaf(w[4],  hb4,  s);
    s = fmaf(w[5],  hb5,  s);
    s = fmaf(w[6],  hb6,  s);
    s = fmaf(w[7],  hb7,  s);
    s = fmaf(w[8],  hb8,  s);
    s = fmaf(w[9],  hb9,  s);
    s = fmaf(w[10], hb10, s);
    s = fmaf(w[11], hb11, s);
    s = fmaf(w[12], hb12, s);
    float r = frcp(1.f + fexp2(s));
    if (lane == 52){
      float4* o4 = (float4*)op;                     // op == out + b*TT + 2040 here
      o4[0] = make_float4(p0,p1,p2,p3);
      o4[1] = make_float4(p4,p5,p6,r);
    }
  }

#undef CONSUME
#undef STEP8
#undef STEP
#undef CAPTURE
#undef FILL
#undef XLOAD
#undef XLO
#undef XHI
}

extern "C" void kernel_launch(void* const* d_in, const int* in_sizes, int n_in,
                              void* d_out, int out_size, void* d_ws, size_t ws_size,
                              hipStream_t stream)
{
  const float* x   = (const float*)d_in[0];
  const float* Wih = (const float*)d_in[1];
  const float* Whh = (const float*)d_in[2];
  const float* bih = (const float*)d_in[3];
  const float* bhh = (const float*)d_in[4];
  const float* fcw = (const float*)d_in[5];
  const float* fcb = (const float*)d_in[6];
  float* out = (float*)d_out;

  (void)d_ws; (void)ws_size;   // fully fused: no workspace
  k_pc<<<dim3(BB), dim3(128), 0, stream>>>(x, Wih, Whh, bih, bhh, fcw, fcb, out);
}